// Round 3
// baseline (1306.208 us; speedup 1.0000x reference)
//
#include <hip/hip_runtime.h>
#include <hip/hip_bf16.h>
#include <stdint.h>

#define N_B 4
#define SEQ 2048
#define NH 16
#define ED 128      // expanded feature dim per head
#define EMB 1024
#define FCK 2048    // NH*ED

typedef float f32x4 __attribute__((ext_vector_type(4)));
typedef _Float16 f16x8 __attribute__((ext_vector_type(8)));
typedef _Float16 f16x4 __attribute__((ext_vector_type(4)));

// ---------------------------------------------------------------------------
// Kernel 1: feature map. One wave per (n,s); the 16 heads are the 16 rows of
// an MFMA tile. z computed with hi/lo fp16 split of BOTH x and fm_w
// (3-term mfma: xh*wh + xh*wl + xl*wh) so z is ~fp32-accurate; exp() amplifies
// z error into feature error, and feature rel-error becomes ABSOLUTE logit
// error scaled by |s| (s up to ~50) downstream.
// Outputs: qf fp16 [nh][s][128] (scaled 1/32 = 1/sqrt(1024)),
//          kh/kl fp16 hi+lo pair (so QK logits are ~exact on the K side),
//          vt fp16 transposed [nh][128][s].
// ---------------------------------------------------------------------------
__global__ __launch_bounds__(256) void fmap_kernel(
    const float* __restrict__ vals, const float* __restrict__ keys,
    const float* __restrict__ qry,  const float* __restrict__ fmw,
    const float* __restrict__ fmb,
    _Float16* __restrict__ qf, _Float16* __restrict__ kh,
    _Float16* __restrict__ kl, _Float16* __restrict__ vt)
{
    const int lane = threadIdx.x & 63;
    const int w = threadIdx.x >> 6;
    const int t = blockIdx.x * 4 + w;      // (n*SEQ + s), 8192 tiles
    const int n = t >> 11;
    const int s = t & 2047;
    const int r = lane & 15;
    const int g = lane >> 4;

    // W fragments (hi/lo): B[d, e] = fm_w[e, d]; lane holds fm_w[te*16+r][j*32+8g+i]
    f16x8 whf[4][2], wlf[4][2];
    #pragma unroll
    for (int te = 0; te < 4; ++te) {
      #pragma unroll
      for (int j = 0; j < 2; ++j) {
        const float* p = fmw + (te*16 + r)*64 + j*32 + 8*g;
        #pragma unroll
        for (int i = 0; i < 8; ++i) {
            float wv = p[i];
            _Float16 hi = (_Float16)wv;
            whf[te][j][i] = hi;
            wlf[te][j][i] = (_Float16)(wv - (float)hi);
        }
      }
    }
    float bias[4];
    #pragma unroll
    for (int te = 0; te < 4; ++te) bias[te] = fmb[te*16 + r];

    const long rowoff = ((long)t*16 + r) * 64;
    const float* srcs[3] = {qry, keys, vals};
    #pragma unroll
    for (int tens = 0; tens < 3; ++tens) {
        const float* src = srcs[tens] + rowoff;
        f16x8 ah[2], al[2];
        #pragma unroll
        for (int j = 0; j < 2; ++j) {
            #pragma unroll
            for (int i = 0; i < 8; ++i) {
                float x = src[j*32 + 8*g + i];
                _Float16 hi = (_Float16)x;
                ah[j][i] = hi;
                al[j][i] = (_Float16)(x - (float)hi);
            }
        }
        #pragma unroll
        for (int te = 0; te < 4; ++te) {
            f32x4 c = (f32x4){0.f,0.f,0.f,0.f};
            c = __builtin_amdgcn_mfma_f32_16x16x32_f16(ah[0], whf[te][0], c, 0, 0, 0);
            c = __builtin_amdgcn_mfma_f32_16x16x32_f16(ah[1], whf[te][1], c, 0, 0, 0);
            c = __builtin_amdgcn_mfma_f32_16x16x32_f16(ah[0], wlf[te][0], c, 0, 0, 0);
            c = __builtin_amdgcn_mfma_f32_16x16x32_f16(ah[1], wlf[te][1], c, 0, 0, 0);
            c = __builtin_amdgcn_mfma_f32_16x16x32_f16(al[0], whf[te][0], c, 0, 0, 0);
            c = __builtin_amdgcn_mfma_f32_16x16x32_f16(al[1], whf[te][1], c, 0, 0, 0);
            // lane holds z[head=4g+i][e = te*16 + r]
            #pragma unroll
            for (int i = 0; i < 4; ++i) {
                float z = c[i] + bias[te];
                float ep = __expf(z), en = __expf(-z);
                int hh = 4*g + i;
                int e = te*16 + r;
                long base = (((long)n*NH + hh)*SEQ + s)*ED;
                if (tens == 0) {
                    qf[base + e]      = (_Float16)(ep * 0.03125f);  // fold 1/sqrt(1024)
                    qf[base + 64 + e] = (_Float16)(en * 0.03125f);
                } else if (tens == 1) {
                    _Float16 hp = (_Float16)ep;
                    _Float16 hn = (_Float16)en;
                    kh[base + e]      = hp;
                    kl[base + e]      = (_Float16)(ep - (float)hp);
                    kh[base + 64 + e] = hn;
                    kl[base + 64 + e] = (_Float16)(en - (float)hn);
                } else {
                    long vb = (((long)n*NH + hh)*ED)*SEQ + s;
                    vt[vb + (long)e*SEQ]        = (_Float16)ep;
                    vt[vb + (long)(64 + e)*SEQ] = (_Float16)en;
                }
            }
        }
    }
}

// ---------------------------------------------------------------------------
// Kernel 2: fc_w fp32 -> fp16
// ---------------------------------------------------------------------------
__global__ __launch_bounds__(256) void cvt_kernel(
    const float* __restrict__ src, _Float16* __restrict__ dst)
{
    long i = ((long)blockIdx.x*256 + threadIdx.x)*8;
    f16x8 o;
    #pragma unroll
    for (int j = 0; j < 8; ++j) o[j] = (_Float16)src[i + j];
    *(f16x8*)(dst + i) = o;
}

// ---------------------------------------------------------------------------
// Kernel 3: flash attention. One wave = 32 q-rows of one (n,h).
// Swapped QK^T: S^T = mfma(A=K, B=Q^T) -> lane holds S[q=lane&15,
// k=4*(lane>>4)+i]. QK uses K hi+lo fp16 split (2 mfma chains) so the only
// logit error is the q-side fp16 rounding (~5e-4 relative). Softmax per
// q-row = 4-reg max + shfl_xor(16,32). P^T is directly the B-operand of
// mfma_f32_16x16x16f16 (classic k=4g+i layout on both sides, verified by
// R2's near-correct run); A-operand is pre-transposed V.
// ---------------------------------------------------------------------------
__global__ __launch_bounds__(256) void attn_kernel(
    const _Float16* __restrict__ qf,
    const _Float16* __restrict__ kh,
    const _Float16* __restrict__ kl,
    const _Float16* __restrict__ vt,
    _Float16* __restrict__ ob)
{
    const int lane = threadIdx.x & 63;
    const int w = threadIdx.x >> 6;
    const int b = blockIdx.x;          // 1024 blocks
    const int nh = b >> 4;             // 0..63
    const int n = nh >> 4, h = nh & 15;
    const int qt = (b & 15)*4 + w;     // 0..63, 32 q-rows each
    const int r = lane & 15, g = lane >> 4;

    const _Float16* qb = qf + (long)nh*SEQ*ED;
    const _Float16* kbh = kh + (long)nh*SEQ*ED;
    const _Float16* kbl = kl + (long)nh*SEQ*ED;
    const _Float16* vb = vt + (long)nh*ED*SEQ;

    f16x8 qfr[2][4];
    #pragma unroll
    for (int u = 0; u < 2; ++u) {
      #pragma unroll
      for (int j = 0; j < 4; ++j)
        qfr[u][j] = *(const f16x8*)(qb + (long)(qt*32 + u*16 + r)*ED + j*32 + 8*g);
    }

    f32x4 acc[2][8];
    #pragma unroll
    for (int u = 0; u < 2; ++u) {
      #pragma unroll
      for (int v2 = 0; v2 < 8; ++v2) acc[u][v2] = (f32x4){0.f,0.f,0.f,0.f};
    }
    float mrun[2] = {-1e30f, -1e30f};
    float lrun[2] = {0.f, 0.f};

    for (int kt = 0; kt < SEQ/16; ++kt) {
        f16x8 khf[4], klf[4];
        #pragma unroll
        for (int j = 0; j < 4; ++j) {
            khf[j] = *(const f16x8*)(kbh + (long)(kt*16 + r)*ED + j*32 + 8*g);
            klf[j] = *(const f16x8*)(kbl + (long)(kt*16 + r)*ED + j*32 + 8*g);
        }
        f16x4 vfr[8];
        #pragma unroll
        for (int v2 = 0; v2 < 8; ++v2)
            vfr[v2] = *(const f16x4*)(vb + (long)(v2*16 + r)*SEQ + kt*16 + 4*g);
        #pragma unroll
        for (int u = 0; u < 2; ++u) {
            f32x4 sc = (f32x4){0.f,0.f,0.f,0.f};
            #pragma unroll
            for (int j = 0; j < 4; ++j)
                sc = __builtin_amdgcn_mfma_f32_16x16x32_f16(khf[j], qfr[u][j], sc, 0, 0, 0);
            #pragma unroll
            for (int j = 0; j < 4; ++j)
                sc = __builtin_amdgcn_mfma_f32_16x16x32_f16(klf[j], qfr[u][j], sc, 0, 0, 0);
            // lane: S[q = qt*32+u*16+r, k = kt*16 + 4g+i] (1/32 folded into qf)
            float mx = fmaxf(fmaxf(sc[0], sc[1]), fmaxf(sc[2], sc[3]));
            mx = fmaxf(mx, __shfl_xor(mx, 16, 64));
            mx = fmaxf(mx, __shfl_xor(mx, 32, 64));
            float mnew = fmaxf(mrun[u], mx);
            float corr = __expf(mrun[u] - mnew);
            mrun[u] = mnew;
            f16x4 pb;
            pb[0] = (_Float16)__expf(sc[0] - mnew);
            pb[1] = (_Float16)__expf(sc[1] - mnew);
            pb[2] = (_Float16)__expf(sc[2] - mnew);
            pb[3] = (_Float16)__expf(sc[3] - mnew);
            // denominator from the SAME rounded p values PV uses
            float rs = (float)pb[0] + (float)pb[1] + (float)pb[2] + (float)pb[3];
            rs += __shfl_xor(rs, 16, 64);
            rs += __shfl_xor(rs, 32, 64);
            lrun[u] = lrun[u]*corr + rs;
            #pragma unroll
            for (int v2 = 0; v2 < 8; ++v2) {
                f32x4 a = acc[u][v2];
                a[0] *= corr; a[1] *= corr; a[2] *= corr; a[3] *= corr;
                acc[u][v2] = __builtin_amdgcn_mfma_f32_16x16x16f16(vfr[v2], pb, a, 0, 0, 0);
            }
        }
    }

    #pragma unroll
    for (int u = 0; u < 2; ++u) {
        float inv = 1.0f / lrun[u];
        int q = qt*32 + u*16 + r;
        long base = ((long)n*SEQ + q)*FCK + h*ED;
        #pragma unroll
        for (int v2 = 0; v2 < 8; ++v2) {
            f16x4 o;
            #pragma unroll
            for (int i = 0; i < 4; ++i) o[i] = (_Float16)(acc[u][v2][i]*inv);
            *(f16x4*)(ob + base + v2*16 + 4*g) = o;   // v = v2*16+4g+i, q fixed
        }
    }
}

// ---------------------------------------------------------------------------
// Kernel 4: out[8192,1024] = ob[8192,2048](fp16) @ fc_w^T(fp16) + fc_b, fp32.
// ---------------------------------------------------------------------------
__global__ __launch_bounds__(256) void fc_kernel(
    const _Float16* __restrict__ ob,
    const _Float16* __restrict__ wt,
    const float* __restrict__ fcb,
    float* __restrict__ out)
{
    const int lane = threadIdx.x & 63;
    const int w = threadIdx.x >> 6;
    const int wid = blockIdx.x*4 + w;   // 8192 waves
    const int mt = wid >> 5;            // 0..255
    const int nt = wid & 31;            // 0..31
    const int r = lane & 15, g = lane >> 4;
    f32x4 acc[2][2];
    #pragma unroll
    for (int u = 0; u < 2; ++u) {
      #pragma unroll
      for (int v = 0; v < 2; ++v) acc[u][v] = (f32x4){0.f,0.f,0.f,0.f};
    }
    for (int kt = 0; kt < FCK/32; ++kt) {
        f16x8 afr[2], bfr[2];
        #pragma unroll
        for (int u = 0; u < 2; ++u)
            afr[u] = *(const f16x8*)(ob + (long)(mt*32 + u*16 + r)*FCK + kt*32 + 8*g);
        #pragma unroll
        for (int v = 0; v < 2; ++v)
            bfr[v] = *(const f16x8*)(wt + (long)(nt*32 + v*16 + r)*FCK + kt*32 + 8*g);
        #pragma unroll
        for (int u = 0; u < 2; ++u) {
          #pragma unroll
          for (int v = 0; v < 2; ++v)
            acc[u][v] = __builtin_amdgcn_mfma_f32_16x16x32_f16(afr[u], bfr[v], acc[u][v], 0, 0, 0);
        }
    }
    #pragma unroll
    for (int u = 0; u < 2; ++u) {
      #pragma unroll
      for (int v = 0; v < 2; ++v) {
        int col = nt*32 + v*16 + r;
        float bias = fcb[col];
        #pragma unroll
        for (int i = 0; i < 4; ++i) {
            int row = mt*32 + u*16 + 4*g + i;
            out[(long)row*EMB + col] = acc[u][v][i] + bias;
        }
      }
    }
}

// ---------------------------------------------------------------------------
extern "C" void kernel_launch(void* const* d_in, const int* in_sizes, int n_in,
                              void* d_out, int out_size, void* d_ws, size_t ws_size,
                              hipStream_t stream) {
    const float* vals = (const float*)d_in[0];
    const float* keys = (const float*)d_in[1];
    const float* qry  = (const float*)d_in[2];
    const float* fmw  = (const float*)d_in[3];
    const float* fmb  = (const float*)d_in[4];
    const float* fcw  = (const float*)d_in[5];
    const float* fcb  = (const float*)d_in[6];
    char* ws = (char*)d_ws;
    const long SZ = 33554432L;                       // 32 MB per fp16 tensor
    _Float16* qf = (_Float16*)(ws);
    _Float16* kh = (_Float16*)(ws + SZ);
    _Float16* kl = (_Float16*)(ws + 2*SZ);
    _Float16* vt = (_Float16*)(ws + 3*SZ);
    _Float16* ob = (_Float16*)(ws + 4*SZ);
    _Float16* wt = (_Float16*)(ws + 5*SZ);           // +4 MB
    float* out = (float*)d_out;

    fmap_kernel<<<dim3(2048), dim3(256), 0, stream>>>(vals, keys, qry, fmw, fmb, qf, kh, kl, vt);
    cvt_kernel<<<dim3(1024), dim3(256), 0, stream>>>(fcw, wt);
    attn_kernel<<<dim3(1024), dim3(256), 0, stream>>>(qf, kh, kl, vt, ob);
    fc_kernel<<<dim3(2048), dim3(256), 0, stream>>>(ob, wt, fcb, out);
}

// Round 4
// 714.138 us; speedup vs baseline: 1.8291x; 1.8291x over previous
//
#include <hip/hip_runtime.h>
#include <hip/hip_bf16.h>
#include <stdint.h>

#define N_B 4
#define SEQ 2048
#define NH 16
#define ED 128      // expanded feature dim per head
#define EMB 1024
#define FCK 2048    // NH*ED

typedef float f32x4 __attribute__((ext_vector_type(4)));
typedef _Float16 f16x8 __attribute__((ext_vector_type(8)));
typedef _Float16 f16x4 __attribute__((ext_vector_type(4)));

__device__ __forceinline__ void gload16(const void* g, void* l) {
    __builtin_amdgcn_global_load_lds(
        (const __attribute__((address_space(1))) uint32_t*)(g),
        (__attribute__((address_space(3))) uint32_t*)(l), 16, 0, 0);
}

// ---------------------------------------------------------------------------
// Kernel 1: feature map. One wave per (n,s); 16 heads = 16 MFMA rows.
// z via hi/lo fp16 split of x and fm_w (3-term) -> ~fp32-accurate z; exp()
// turns z error into relative feature error, which becomes ABSOLUTE logit
// error scaled by |s| (~30) downstream.
// Outputs: qf fp16 [nh][s][128] (scaled 1/32), kf fp16 (single precision is
// enough: rel 2^-11 -> logit err ~0.03), vt fp16 transposed [nh][128][s].
// ---------------------------------------------------------------------------
__global__ __launch_bounds__(256) void fmap_kernel(
    const float* __restrict__ vals, const float* __restrict__ keys,
    const float* __restrict__ qry,  const float* __restrict__ fmw,
    const float* __restrict__ fmb,
    _Float16* __restrict__ qf, _Float16* __restrict__ kf,
    _Float16* __restrict__ vt)
{
    const int lane = threadIdx.x & 63;
    const int w = threadIdx.x >> 6;
    const int t = blockIdx.x * 4 + w;      // (n*SEQ + s)
    const int n = t >> 11;
    const int s = t & 2047;
    const int r = lane & 15;
    const int g = lane >> 4;

    f16x8 whf[4][2], wlf[4][2];
    #pragma unroll
    for (int te = 0; te < 4; ++te) {
      #pragma unroll
      for (int j = 0; j < 2; ++j) {
        const float* p = fmw + (te*16 + r)*64 + j*32 + 8*g;
        #pragma unroll
        for (int i = 0; i < 8; ++i) {
            float wv = p[i];
            _Float16 hi = (_Float16)wv;
            whf[te][j][i] = hi;
            wlf[te][j][i] = (_Float16)(wv - (float)hi);
        }
      }
    }
    float bias[4];
    #pragma unroll
    for (int te = 0; te < 4; ++te) bias[te] = fmb[te*16 + r];

    const long rowoff = ((long)t*16 + r) * 64;
    const float* srcs[3] = {qry, keys, vals};
    #pragma unroll
    for (int tens = 0; tens < 3; ++tens) {
        const float* src = srcs[tens] + rowoff;
        f16x8 ah[2], al[2];
        #pragma unroll
        for (int j = 0; j < 2; ++j) {
            #pragma unroll
            for (int i = 0; i < 8; ++i) {
                float x = src[j*32 + 8*g + i];
                _Float16 hi = (_Float16)x;
                ah[j][i] = hi;
                al[j][i] = (_Float16)(x - (float)hi);
            }
        }
        #pragma unroll
        for (int te = 0; te < 4; ++te) {
            f32x4 c = (f32x4){0.f,0.f,0.f,0.f};
            c = __builtin_amdgcn_mfma_f32_16x16x32_f16(ah[0], whf[te][0], c, 0, 0, 0);
            c = __builtin_amdgcn_mfma_f32_16x16x32_f16(ah[1], whf[te][1], c, 0, 0, 0);
            c = __builtin_amdgcn_mfma_f32_16x16x32_f16(ah[0], wlf[te][0], c, 0, 0, 0);
            c = __builtin_amdgcn_mfma_f32_16x16x32_f16(ah[1], wlf[te][1], c, 0, 0, 0);
            c = __builtin_amdgcn_mfma_f32_16x16x32_f16(al[0], whf[te][0], c, 0, 0, 0);
            c = __builtin_amdgcn_mfma_f32_16x16x32_f16(al[1], whf[te][1], c, 0, 0, 0);
            #pragma unroll
            for (int i = 0; i < 4; ++i) {
                float z = c[i] + bias[te];
                float ep = __expf(z), en = __expf(-z);
                int hh = 4*g + i;
                int e = te*16 + r;
                long base = (((long)n*NH + hh)*SEQ + s)*ED;
                if (tens == 0) {
                    qf[base + e]      = (_Float16)(ep * 0.03125f);  // fold 1/sqrt(1024)
                    qf[base + 64 + e] = (_Float16)(en * 0.03125f);
                } else if (tens == 1) {
                    kf[base + e]      = (_Float16)ep;
                    kf[base + 64 + e] = (_Float16)en;
                } else {
                    long vb = (((long)n*NH + hh)*ED)*SEQ + s;
                    vt[vb + (long)e*SEQ]        = (_Float16)ep;
                    vt[vb + (long)(64 + e)*SEQ] = (_Float16)en;
                }
            }
        }
    }
}

// ---------------------------------------------------------------------------
// Kernel 2: fc_w fp32 -> fp16
// ---------------------------------------------------------------------------
__global__ __launch_bounds__(256) void cvt_kernel(
    const float* __restrict__ src, _Float16* __restrict__ dst)
{
    long i = ((long)blockIdx.x*256 + threadIdx.x)*8;
    f16x8 o;
    #pragma unroll
    for (int j = 0; j < 8; ++j) o[j] = (_Float16)src[i + j];
    *(f16x8*)(dst + i) = o;
}

// ---------------------------------------------------------------------------
// Kernel 3: flash attention, KVBLK=64, LDS-staged K/V (double-buffered,
// global_load_lds with pre-swizzled global source; XOR chunk swizzle:
// K chunk16 c stores global chunk c^(row&15); V chunk16 c stores c^(row&7)).
// 4 waves/block share one (n,h) K/V stream; wave w owns 32 q-rows.
// Swapped QK^T: lane holds S[q=r, k=4g+i] per 16-col chunk; softmax reduce
// once per 64 cols (4x fewer shfl/rescale than per-16).
// LDS 64 KB -> 2 blocks/CU.
// ---------------------------------------------------------------------------
__global__ __launch_bounds__(256) void attn_kernel(
    const _Float16* __restrict__ qf,
    const _Float16* __restrict__ kf,
    const _Float16* __restrict__ vt,
    _Float16* __restrict__ ob)
{
    __shared__ char smem[65536];
    const int lane = threadIdx.x & 63;
    const int w = threadIdx.x >> 6;
    const int b = blockIdx.x;          // 1024 blocks
    const int nh = b >> 4;
    const int n = nh >> 4, h = nh & 15;
    const int qt = (b & 15)*4 + w;     // 32 q-rows per wave
    const int r = lane & 15, g = lane >> 4;

    const _Float16* qb = qf + (long)nh*SEQ*ED;
    const char* kg = (const char*)(kf + (long)nh*SEQ*ED);   // row = 256 B
    const char* vg = (const char*)(vt + (long)nh*ED*SEQ);   // row = SEQ*2 B

    f16x8 qfr[2][4];
    #pragma unroll
    for (int u = 0; u < 2; ++u) {
      #pragma unroll
      for (int j = 0; j < 4; ++j)
        qfr[u][j] = *(const f16x8*)(qb + (long)(qt*32 + u*16 + r)*ED + j*32 + 8*g);
    }

    // cooperative stage of one 64-row K/V tile into buffer bsel
    auto stage = [&](int kt, int bsel) {
        char* Kl = smem + bsel*32768;
        char* Vl = Kl + 16384;
        const char* kts = kg + (long)kt*64*256;
        const char* vts = vg + (long)kt*64*2;
        #pragma unroll
        for (int i = 0; i < 4; ++i) {                 // K rows [w*16, w*16+16)
            int row = w*16 + i*4 + (lane>>4);
            int c = (lane&15) ^ (row&15);
            gload16(kts + (long)row*256 + c*16, Kl + (w*16 + i*4)*256);
        }
        #pragma unroll
        for (int i = 0; i < 4; ++i) {                 // V rows [w*32, w*32+32)
            int row = w*32 + i*8 + (lane>>3);
            int c = (lane&7) ^ (row&7);
            gload16(vts + (long)row*(SEQ*2) + c*16, Vl + (w*32 + i*8)*128);
        }
    };

    f32x4 acc[2][8];
    #pragma unroll
    for (int u = 0; u < 2; ++u)
      #pragma unroll
      for (int v2 = 0; v2 < 8; ++v2) acc[u][v2] = (f32x4){0.f,0.f,0.f,0.f};
    float mrun[2] = {-1e30f, -1e30f};
    float lrun[2] = {0.f, 0.f};

    stage(0, 0);
    __syncthreads();

    for (int kt = 0; kt < SEQ/64; ++kt) {
        const int cur = kt & 1;
        if (kt + 1 < SEQ/64) stage(kt + 1, cur ^ 1);
        const _Float16* Kl = (const _Float16*)(smem + cur*32768);
        const _Float16* Vl = Kl + 8192;

        // QK^T for 64 columns
        f32x4 sc4[2][4];
        #pragma unroll
        for (int c4 = 0; c4 < 4; ++c4) {
            f16x8 khf[4];
            #pragma unroll
            for (int j = 0; j < 4; ++j)
                khf[j] = *(const f16x8*)(Kl + (c4*16 + r)*128 + (((j*4 + g) ^ r) << 3));
            #pragma unroll
            for (int u = 0; u < 2; ++u) {
                f32x4 s = (f32x4){0.f,0.f,0.f,0.f};
                #pragma unroll
                for (int j = 0; j < 4; ++j)
                    s = __builtin_amdgcn_mfma_f32_16x16x32_f16(khf[j], qfr[u][j], s, 0, 0, 0);
                sc4[u][c4] = s;
            }
        }

        // online softmax, one reduce/rescale per 64 columns
        f16x4 pbv[2][4];
        #pragma unroll
        for (int u = 0; u < 2; ++u) {
            float mx = sc4[u][0][0];
            #pragma unroll
            for (int c4 = 0; c4 < 4; ++c4)
                #pragma unroll
                for (int i2 = 0; i2 < 4; ++i2) mx = fmaxf(mx, sc4[u][c4][i2]);
            mx = fmaxf(mx, __shfl_xor(mx, 16, 64));
            mx = fmaxf(mx, __shfl_xor(mx, 32, 64));
            float mnew = fmaxf(mrun[u], mx);
            float corr = __expf(mrun[u] - mnew);
            float rs = 0.f;
            #pragma unroll
            for (int c4 = 0; c4 < 4; ++c4) {
                f16x4 p;
                #pragma unroll
                for (int i2 = 0; i2 < 4; ++i2) {
                    float pv = __expf(sc4[u][c4][i2] - mnew);
                    p[i2] = (_Float16)pv;
                    rs += (float)p[i2];            // denom from rounded p
                }
                pbv[u][c4] = p;
            }
            rs += __shfl_xor(rs, 16, 64);
            rs += __shfl_xor(rs, 32, 64);
            lrun[u] = lrun[u]*corr + rs;
            mrun[u] = mnew;
            #pragma unroll
            for (int v2 = 0; v2 < 8; ++v2) {
                acc[u][v2][0] *= corr; acc[u][v2][1] *= corr;
                acc[u][v2][2] *= corr; acc[u][v2][3] *= corr;
            }
        }

        // PV: 64-col tile in 4 sub-chunks of 16
        #pragma unroll
        for (int kq = 0; kq < 4; ++kq) {
            f16x4 vfr[8];
            #pragma unroll
            for (int v2 = 0; v2 < 8; ++v2)
                vfr[v2] = *(const f16x4*)(Vl + (v2*16 + r)*64 +
                            ((((kq*2 + (g>>1)) ^ (r&7)) << 3) + ((g&1) << 2)));
            #pragma unroll
            for (int u = 0; u < 2; ++u)
                #pragma unroll
                for (int v2 = 0; v2 < 8; ++v2)
                    acc[u][v2] = __builtin_amdgcn_mfma_f32_16x16x16f16(vfr[v2], pbv[u][kq], acc[u][v2], 0, 0, 0);
        }
        __syncthreads();   // drains vmcnt (stage kt+1 done) + protects buffers
    }

    #pragma unroll
    for (int u = 0; u < 2; ++u) {
        float inv = 1.0f / lrun[u];
        int q = qt*32 + u*16 + r;
        long base = ((long)n*SEQ + q)*FCK + h*ED;
        #pragma unroll
        for (int v2 = 0; v2 < 8; ++v2) {
            f16x4 o;
            #pragma unroll
            for (int i = 0; i < 4; ++i) o[i] = (_Float16)(acc[u][v2][i]*inv);
            *(f16x4*)(ob + base + v2*16 + 4*g) = o;
        }
    }
}

// ---------------------------------------------------------------------------
// Kernel 4: out[8192,1024] = ob[8192,2048](fp16) @ fc_w^T(fp16) + fc_b, fp32.
// ---------------------------------------------------------------------------
__global__ __launch_bounds__(256) void fc_kernel(
    const _Float16* __restrict__ ob,
    const _Float16* __restrict__ wt,
    const float* __restrict__ fcb,
    float* __restrict__ out)
{
    const int lane = threadIdx.x & 63;
    const int w = threadIdx.x >> 6;
    const int wid = blockIdx.x*4 + w;
    const int mt = wid >> 5;
    const int nt = wid & 31;
    const int r = lane & 15, g = lane >> 4;
    f32x4 acc[2][2];
    #pragma unroll
    for (int u = 0; u < 2; ++u)
      #pragma unroll
      for (int v = 0; v < 2; ++v) acc[u][v] = (f32x4){0.f,0.f,0.f,0.f};
    for (int kt = 0; kt < FCK/32; ++kt) {
        f16x8 afr[2], bfr[2];
        #pragma unroll
        for (int u = 0; u < 2; ++u)
            afr[u] = *(const f16x8*)(ob + (long)(mt*32 + u*16 + r)*FCK + kt*32 + 8*g);
        #pragma unroll
        for (int v = 0; v < 2; ++v)
            bfr[v] = *(const f16x8*)(wt + (long)(nt*32 + v*16 + r)*FCK + kt*32 + 8*g);
        #pragma unroll
        for (int u = 0; u < 2; ++u)
          #pragma unroll
          for (int v = 0; v < 2; ++v)
            acc[u][v] = __builtin_amdgcn_mfma_f32_16x16x32_f16(afr[u], bfr[v], acc[u][v], 0, 0, 0);
    }
    #pragma unroll
    for (int u = 0; u < 2; ++u)
      #pragma unroll
      for (int v = 0; v < 2; ++v) {
        int col = nt*32 + v*16 + r;
        float bias = fcb[col];
        #pragma unroll
        for (int i = 0; i < 4; ++i) {
            int row = mt*32 + u*16 + 4*g + i;
            out[(long)row*EMB + col] = acc[u][v][i] + bias;
        }
      }
}

// ---------------------------------------------------------------------------
extern "C" void kernel_launch(void* const* d_in, const int* in_sizes, int n_in,
                              void* d_out, int out_size, void* d_ws, size_t ws_size,
                              hipStream_t stream) {
    const float* vals = (const float*)d_in[0];
    const float* keys = (const float*)d_in[1];
    const float* qry  = (const float*)d_in[2];
    const float* fmw  = (const float*)d_in[3];
    const float* fmb  = (const float*)d_in[4];
    const float* fcw  = (const float*)d_in[5];
    const float* fcb  = (const float*)d_in[6];
    char* ws = (char*)d_ws;
    const long SZ = 33554432L;                       // 32 MB per fp16 tensor
    _Float16* qf = (_Float16*)(ws);
    _Float16* kf = (_Float16*)(ws + SZ);
    _Float16* vt = (_Float16*)(ws + 2*SZ);
    _Float16* ob = (_Float16*)(ws + 3*SZ);
    _Float16* wt = (_Float16*)(ws + 4*SZ);           // +4 MB
    float* out = (float*)d_out;

    fmap_kernel<<<dim3(2048), dim3(256), 0, stream>>>(vals, keys, qry, fmw, fmb, qf, kf, vt);
    cvt_kernel<<<dim3(1024), dim3(256), 0, stream>>>(fcw, wt);
    attn_kernel<<<dim3(1024), dim3(256), 0, stream>>>(qf, kf, vt, ob);
    fc_kernel<<<dim3(2048), dim3(256), 0, stream>>>(ob, wt, fcb, out);
}